// Round 4
// baseline (624881.787 us; speedup 1.0000x reference)
//
#include <hip/hip_runtime.h>
#include <math.h>

// LSTMModel: 2048 sequential steps, 2x LSTMCell(H=512), LN(64) front, fc(512->1).
// R3: XCD-colocated sync. Runtime XCC_ID rendezvous assigns layer-1's 32 blocks to one
// XCD and layer-0's 16 to another; same-XCD data-as-flag sync uses plain stores +
// sc0 (L1-bypass, L2-served) polls (~200ns hop) instead of device-scope (~1.5us).
// Cross-XCD h0 handoff stays agent-scope (constant pipeline offset, not in a chain).
// Timeout + bounded-poll fallback -> agent-scope everywhere (identical arithmetic).

#define H      512
#define G4     2048
#define WIN    64
#define STEPS  2048
#define NL0    16
#define NL1    32
#define TPB    512
#define NBLK   256
#define POISON 0xFFFFFFFFu
#define K_EXIT 0
#define K_L0   1
#define K_L1   2
#define RDV_TIMEOUT 3000000LL

__device__ __forceinline__ float sigf(float x)     { return 1.0f / (1.0f + __expf(-x)); }
__device__ __forceinline__ float tanhfast(float x) { return 2.0f / (1.0f + __expf(-2.0f * x)) - 1.0f; }

// ---- coherence-scoped load/store helpers ----
__device__ __forceinline__ uint4 ld4_sc01(const unsigned int* p) {
    uint4 v;
    asm volatile("global_load_dwordx4 %0, %1, off sc0 sc1\n\ts_waitcnt vmcnt(0)"
                 : "=&v"(v) : "v"(p) : "memory");
    return v;
}
__device__ __forceinline__ uint4 ld4_sc0(const unsigned int* p) {
    uint4 v;
    asm volatile("global_load_dwordx4 %0, %1, off sc0\n\ts_waitcnt vmcnt(0)"
                 : "=&v"(v) : "v"(p) : "memory");
    return v;
}
__device__ __forceinline__ unsigned int ld1_sc01(const unsigned int* p) {
    unsigned int v;
    asm volatile("global_load_dword %0, %1, off sc0 sc1\n\ts_waitcnt vmcnt(0)"
                 : "=&v"(v) : "v"(p) : "memory");
    return v;
}
__device__ __forceinline__ void st1_sc01(unsigned int* p, unsigned int v) {
    asm volatile("global_store_dword %0, %1, off sc0 sc1" :: "v"(p), "v"(v) : "memory");
}
__device__ __forceinline__ void st1_plain(unsigned int* p, unsigned int v) {
    asm volatile("global_store_dword %0, %1, off" :: "v"(p), "v"(v) : "memory");
}
__device__ __forceinline__ bool ok4(uint4 v) {
    return v.x != POISON && v.y != POISON && v.z != POISON && v.w != POISON;
}
__device__ __forceinline__ void lds_put4(float* dst, uint4 v) {
    float4 f;
    f.x = __uint_as_float(v.x); f.y = __uint_as_float(v.y);
    f.z = __uint_as_float(v.z); f.w = __uint_as_float(v.w);
    *(float4*)dst = f;
}

// ---------------- LayerNorm over sliding windows (parallel over t) ----------------
__global__ void ln_kernel(const float* __restrict__ batch, const float* __restrict__ lnw,
                          const float* __restrict__ lnb, float* __restrict__ lnx) {
    int wave = threadIdx.x >> 6;
    int lane = threadIdx.x & 63;
    int t = blockIdx.x * 4 + wave;
    int src = t - 63 + lane;
    float v = (src >= 0) ? batch[src] : 0.0f;
    float s = v, ss = v * v;
    #pragma unroll
    for (int m = 32; m >= 1; m >>= 1) { s += __shfl_xor(s, m); ss += __shfl_xor(ss, m); }
    float mu   = s * (1.0f / 64.0f);
    float var  = ss * (1.0f / 64.0f) - mu * mu;
    float rstd = rsqrtf(var + 1e-5f);
    lnx[t * WIN + lane] = (v - mu) * rstd * lnw[lane] + lnb[lane];
}

// ------------- precomp0[t][r] = Wih0[r,:] . lnx[t,:] + bih0[r] + bhh0[r] ----------
__global__ __launch_bounds__(256) void precomp_kernel(
    const float* __restrict__ Wih0, const float* __restrict__ bih0,
    const float* __restrict__ bhh0, const float* __restrict__ lnx,
    float* __restrict__ pre) {
    __shared__ float Wt[64][65];
    __shared__ float Xt[64][64];
    int r0 = blockIdx.x * 64;
    int t0 = blockIdx.y * 64;
    for (int i = threadIdx.x; i < 4096; i += 256) Wt[i >> 6][i & 63] = Wih0[r0 * 64 + i];
    for (int i = threadIdx.x; i < 4096; i += 256) Xt[i >> 6][i & 63] = lnx[t0 * 64 + i];
    __syncthreads();
    int lane = threadIdx.x & 63;
    int wv   = threadIdx.x >> 6;
    int row  = r0 + lane;
    float bias = bih0[row] + bhh0[row];
    for (int j = 0; j < 16; ++j) {
        int tl = wv * 16 + j;
        float acc = bias;
        #pragma unroll 8
        for (int k = 0; k < 64; ++k) acc += Wt[lane][k] * Xt[tl][k];
        pre[(size_t)(t0 + tl) * G4 + row] = acc;
    }
}

// ---------------- persistent recurrent kernel with runtime XCD role assignment ----------------
__global__ __launch_bounds__(TPB, 2) void recur_kernel(
    const float* __restrict__ Whh0,
    const float* __restrict__ Wih1, const float* __restrict__ Whh1,
    const float* __restrict__ bih1, const float* __restrict__ bhh1,
    const float* __restrict__ fcw,  const float* __restrict__ pre,
    unsigned int* h0u, unsigned int* h1u,      // [STEPS+1][H], NaN-poisoned
    unsigned int* xcctab, unsigned int* roles, // [NBLK] each, poisoned
    float* __restrict__ pout) {                // [STEPS][NL1]
    const int tid = threadIdx.x;
    const int bid = blockIdx.x;
    __shared__ unsigned int xl[NBLK];
    __shared__ unsigned int role_s;

    // ---- publish my XCD id ----
    if (tid == 0) {
        unsigned int xcc = __builtin_amdgcn_s_getreg((31u << 11) | 20u) & 0xFu; // HW_REG_XCC_ID
        st1_sc01(&xcctab[bid], xcc);
    }

    // ---- leader (block 0) assigns roles ----
    if (bid == 0) {
        unsigned int myv = POISON;
        long long start = clock64();
        while (true) {
            if (tid < NBLK && myv == POISON) myv = ld1_sc01(&xcctab[tid]);
            int nv = __syncthreads_count((tid < NBLK) ? (myv != POISON) : 0);
            if (nv == NBLK) break;
            if (nv >= (NL0 + NL1) && (clock64() - start) > RDV_TIMEOUT) break;
        }
        if (tid < NBLK) xl[tid] = myv;
        __syncthreads();
        if (tid == 0) {
            int cnt[8] = {0,0,0,0,0,0,0,0};
            for (int i = 0; i < NBLK; ++i)
                if (xl[i] != POISON && xl[i] < 8) cnt[xl[i]]++;
            int XB = -1, XA = -1;
            for (int x = 0; x < 8; ++x)
                if (cnt[x] >= NL1 && (XB < 0 || cnt[x] > cnt[XB])) XB = x;
            for (int x = 0; x < 8; ++x)
                if (x != XB && cnt[x] >= NL0 && (XA < 0 || cnt[x] > cnt[XA])) XA = x;
            const int fastp = (XB >= 0 && XA >= 0) ? 1 : 0;
            int n0 = 0, n1 = 0;
            for (int i = 0; i < NBLK; ++i) {
                unsigned int r = (K_EXIT << 8);
                if (fastp) {
                    if (xl[i] == (unsigned)XA && n0 < NL0)      r = (1u << 12) | (K_L0 << 8) | (unsigned)n0++;
                    else if (xl[i] == (unsigned)XB && n1 < NL1) r = (1u << 12) | (K_L1 << 8) | (unsigned)n1++;
                } else if (xl[i] != POISON) {
                    if (n0 < NL0)      r = (K_L0 << 8) | (unsigned)n0++;
                    else if (n1 < NL1) r = (K_L1 << 8) | (unsigned)n1++;
                }
                st1_sc01(&roles[i], r);
            }
        }
    }

    // ---- read my role ----
    if (tid == 0) {
        unsigned int r;
        do { r = ld1_sc01(&roles[bid]); } while (r == POISON);
        role_s = r;
    }
    __syncthreads();
    const unsigned int role = role_s;
    const int  kind = (role >> 8) & 0xF;
    const bool fast = ((role >> 12) & 1) != 0;
    const int  slot = role & 0xFF;
    if (kind == K_EXIT) return;

    const int LG = tid >> 5;
    const int s  = tid & 31;

    if (kind == K_L0) {
        // ---------------- layer-0: 32 units/block ----------------
        __shared__ float hA[2][H];
        __shared__ float preb[2][128];
        const int u0 = slot * 32;
        float w0[8][16];
        #pragma unroll
        for (int j = 0; j < 8; ++j) {
            int row = (j & 3) * H + u0 + 2 * LG + (j >> 2);
            #pragma unroll
            for (int i = 0; i < 16; ++i) w0[j][i] = Whh0[(size_t)row * H + i * 32 + s];
        }
        float c0 = 0.0f;

        for (int t = 0; t < STEPS; ++t) {
            const int pb = t & 1;
            float prereg = 0.0f;
            if (tid < 128)
                prereg = pre[(size_t)t * G4 + (tid >> 5) * H + u0 + (tid & 31)];
            if (tid < 128) {
                if (t > 0) {
                    unsigned int* p = h0u + (size_t)t * H + tid * 4;
                    uint4 v; int tries = 0;
                    do {
                        v = (fast && tries < 2048) ? ld4_sc0(p) : ld4_sc01(p);
                        ++tries;
                    } while (!ok4(v));
                    lds_put4(&hA[pb][tid * 4], v);
                } else {
                    *(float4*)&hA[pb][tid * 4] = make_float4(0.f, 0.f, 0.f, 0.f);
                }
                preb[pb][tid] = prereg;
            }
            __syncthreads();

            float acc[8];
            #pragma unroll
            for (int j = 0; j < 8; ++j) {
                float a = 0.0f;
                #pragma unroll
                for (int i = 0; i < 16; ++i) a += w0[j][i] * hA[pb][i * 32 + s];
                acc[j] = a;
            }
            #pragma unroll
            for (int m = 16; m >= 1; m >>= 1) {
                #pragma unroll
                for (int j = 0; j < 8; ++j) acc[j] += __shfl_xor(acc[j], m);
            }
            if (s < 2) {
                const int ul = 2 * LG + s;
                const int base = s * 4;
                float iv = sigf(acc[base + 0] + preb[pb][0 * 32 + ul]);
                float fv = sigf(acc[base + 1] + preb[pb][1 * 32 + ul]);
                float gv = tanhfast(acc[base + 2] + preb[pb][2 * 32 + ul]);
                float ov = sigf(acc[base + 3] + preb[pb][3 * 32 + ul]);
                c0 = fv * c0 + iv * gv;
                float h = ov * tanhfast(c0);
                unsigned int hb = __float_as_uint(h);
                unsigned int* p = h0u + (size_t)(t + 1) * H + u0 + ul;
                st1_sc01(p, hb);            // MALL: layer-1 (cross-XCD) + slow-path peers
                if (fast) st1_plain(p, hb); // local L2: fast-path peers
            }
        }
    } else {
        // ---------------- layer-1: 16 units/block ----------------
        __shared__ float hA2[2][H];
        __shared__ float hB2[2][H];
        __shared__ float facc[16];
        const int u0 = slot * 16;
        float w1[4][16], w2[4][16], bias[4];
        #pragma unroll
        for (int j = 0; j < 4; ++j) {
            int row = j * H + u0 + LG;
            bias[j] = bih1[row] + bhh1[row];
            #pragma unroll
            for (int i = 0; i < 16; ++i) {
                w1[j][i] = Wih1[(size_t)row * H + i * 32 + s];
                w2[j][i] = Whh1[(size_t)row * H + i * 32 + s];
            }
        }
        const float fcv = fcw[u0 + LG];
        float c1 = 0.0f;

        for (int t = 0; t < STEPS; ++t) {
            const int pb = t & 1;
            if (tid < 128) {
                unsigned int* pa = h0u + (size_t)(t + 1) * H + tid * 4;
                uint4 va; bool da = false;
                if (t > 0) {
                    unsigned int* pbp = h1u + (size_t)t * H + tid * 4;
                    uint4 vb; bool db = false; int tries = 0;
                    do {
                        if (!da) { va = ld4_sc01(pa); da = ok4(va); }
                        if (!db) {
                            vb = (fast && tries < 2048) ? ld4_sc0(pbp) : ld4_sc01(pbp);
                            db = ok4(vb);
                        }
                        ++tries;
                    } while (!(da && db));
                    lds_put4(&hB2[pb][tid * 4], vb);
                } else {
                    do { va = ld4_sc01(pa); da = ok4(va); } while (!da);
                    *(float4*)&hB2[pb][tid * 4] = make_float4(0.f, 0.f, 0.f, 0.f);
                }
                lds_put4(&hA2[pb][tid * 4], va);
            }
            __syncthreads();

            float acc[4];
            #pragma unroll
            for (int j = 0; j < 4; ++j) {
                float a = 0.0f;
                #pragma unroll
                for (int i = 0; i < 16; ++i)
                    a += w1[j][i] * hA2[pb][i * 32 + s] + w2[j][i] * hB2[pb][i * 32 + s];
                acc[j] = a;
            }
            #pragma unroll
            for (int m = 16; m >= 1; m >>= 1) {
                #pragma unroll
                for (int j = 0; j < 4; ++j) acc[j] += __shfl_xor(acc[j], m);
            }
            if (s == 0) {
                float iv = sigf(acc[0] + bias[0]);
                float fv = sigf(acc[1] + bias[1]);
                float gv = tanhfast(acc[2] + bias[2]);
                float ov = sigf(acc[3] + bias[3]);
                c1 = fv * c1 + iv * gv;
                float h = ov * tanhfast(c1);
                unsigned int hb = __float_as_uint(h);
                unsigned int* p = h1u + (size_t)(t + 1) * H + u0 + LG;
                if (fast) st1_plain(p, hb); else st1_sc01(p, hb);
                facc[LG] = fmaxf(h, 0.0f) * fcv;
            }
            __syncthreads();
            if (tid == 0) {
                float pp = 0.0f;
                #pragma unroll
                for (int u = 0; u < 16; ++u) pp += facc[u];
                pout[(size_t)t * NL1 + slot] = pp;
            }
        }
    }
}

// ---------------- reduce NL1 partials per step -> out[t] ----------------
__global__ void reduce_out(const float* __restrict__ pout, const float* __restrict__ fcb,
                           float* __restrict__ out) {
    int t = blockIdx.x;
    int l = threadIdx.x;                 // 64 threads
    float v = (l < NL1) ? pout[(size_t)t * NL1 + l] : 0.0f;
    #pragma unroll
    for (int m = 16; m >= 1; m >>= 1) v += __shfl_xor(v, m);
    if (l == 0) out[t] = v + fcb[0];
}

extern "C" void kernel_launch(void* const* d_in, const int* in_sizes, int n_in,
                              void* d_out, int out_size, void* d_ws, size_t ws_size,
                              hipStream_t stream) {
    const float* batch = (const float*)d_in[0];
    const float* Wih0  = (const float*)d_in[1];
    const float* Whh0  = (const float*)d_in[2];
    const float* bih0  = (const float*)d_in[3];
    const float* bhh0  = (const float*)d_in[4];
    const float* Wih1  = (const float*)d_in[5];
    const float* Whh1  = (const float*)d_in[6];
    const float* bih1  = (const float*)d_in[7];
    const float* bhh1  = (const float*)d_in[8];
    const float* lnw   = (const float*)d_in[9];
    const float* lnb   = (const float*)d_in[10];
    const float* fcw   = (const float*)d_in[11];
    const float* fcb   = (const float*)d_in[12];
    float* out = (float*)d_out;

    // workspace layout (~26.0 MB)
    float*        ws   = (float*)d_ws;
    float*        pre  = ws;                                   // 2048*2048
    float*        lnx  = pre + (size_t)STEPS * G4;             // 2048*64
    float*        pout = lnx + (size_t)STEPS * WIN;            // 2048*NL1
    unsigned int* h0u  = (unsigned int*)(pout + (size_t)STEPS * NL1);  // 2049*512
    unsigned int* h1u  = h0u + (size_t)(STEPS + 1) * H;        // 2049*512
    unsigned int* xcct = h1u + (size_t)(STEPS + 1) * H;        // 256
    unsigned int* rol  = xcct + NBLK;                          // 256

    // poison h histories + rendezvous tables in one contiguous memset
    hipMemsetAsync(h0u, 0xFF,
                   ((size_t)2 * (STEPS + 1) * H + 2 * NBLK) * sizeof(unsigned int), stream);

    ln_kernel<<<dim3(STEPS / 4), dim3(256), 0, stream>>>(batch, lnw, lnb, lnx);
    precomp_kernel<<<dim3(G4 / 64, STEPS / 64), dim3(256), 0, stream>>>(Wih0, bih0, bhh0, lnx, pre);
    recur_kernel<<<dim3(NBLK), dim3(TPB), 0, stream>>>(Whh0, Wih1, Whh1, bih1, bhh1,
                                                       fcw, pre, h0u, h1u, xcct, rol, pout);
    reduce_out<<<dim3(STEPS), dim3(64), 0, stream>>>(pout, fcb, out);
}

// Round 6
// 6390.939 us; speedup vs baseline: 97.7762x; 97.7762x over previous
//
#include <hip/hip_runtime.h>
#include <math.h>

// LSTMModel: 2048 sequential steps, 2x LSTMCell(H=512), LN(64) front, fc(512->1).
// R5 = R4 with compile fix: inline-asm vector operands must be ext_vector_type
// (struct uint4 as asm INPUT "v" fails: "indirect register inputs").
// R4 changes vs R2: (1) weights pinned in VGPRs via asm (poll memory-clobbers can't
// force reloads); (2) packed dwordx4/x2 h publication via wave shfl-gather;
// (3) x4 polls in both layers; (4) register-double-buffered pre prefetch.

#define H      512
#define G4     2048
#define WIN    64
#define STEPS  2048
#define NA     16      // layer-0 blocks (32 units each)
#define NB     32      // layer-1 blocks (16 units each)
#define TPB    512
#define POISON 0xFFFFFFFFu

#define KEEP(x) asm volatile("" : "+v"(x))

typedef unsigned int u32x4 __attribute__((ext_vector_type(4)));
typedef unsigned int u32x2 __attribute__((ext_vector_type(2)));

__device__ __forceinline__ float sigf(float x)     { return 1.0f / (1.0f + __expf(-x)); }
__device__ __forceinline__ float tanhfast(float x) { return 2.0f / (1.0f + __expf(-2.0f * x)) - 1.0f; }

// ---- MALL-visible (agent-scope) load/store helpers ----
__device__ __forceinline__ u32x4 ld4_sc01(const unsigned int* p) {
    u32x4 v;
    asm volatile("global_load_dwordx4 %0, %1, off sc0 sc1\n\ts_waitcnt vmcnt(0)"
                 : "=&v"(v) : "v"(p) : "memory");
    return v;
}
__device__ __forceinline__ void st4_sc01(unsigned int* p, u32x4 v) {
    asm volatile("global_store_dwordx4 %0, %1, off sc0 sc1" :: "v"(p), "v"(v) : "memory");
}
__device__ __forceinline__ void st2_sc01(unsigned int* p, u32x2 v) {
    asm volatile("global_store_dwordx2 %0, %1, off sc0 sc1" :: "v"(p), "v"(v) : "memory");
}
__device__ __forceinline__ bool ok4(u32x4 v) {
    return v.x != POISON && v.y != POISON && v.z != POISON && v.w != POISON;
}
__device__ __forceinline__ void lds_put4(float* dst, u32x4 v) {
    float4 f;
    f.x = __uint_as_float(v.x); f.y = __uint_as_float(v.y);
    f.z = __uint_as_float(v.z); f.w = __uint_as_float(v.w);
    *(float4*)dst = f;
}

// ---------------- LayerNorm over sliding windows (parallel over t) ----------------
__global__ void ln_kernel(const float* __restrict__ batch, const float* __restrict__ lnw,
                          const float* __restrict__ lnb, float* __restrict__ lnx) {
    int wave = threadIdx.x >> 6;
    int lane = threadIdx.x & 63;
    int t = blockIdx.x * 4 + wave;
    int src = t - 63 + lane;
    float v = (src >= 0) ? batch[src] : 0.0f;
    float s = v, ss = v * v;
    #pragma unroll
    for (int m = 32; m >= 1; m >>= 1) { s += __shfl_xor(s, m); ss += __shfl_xor(ss, m); }
    float mu   = s * (1.0f / 64.0f);
    float var  = ss * (1.0f / 64.0f) - mu * mu;
    float rstd = rsqrtf(var + 1e-5f);
    lnx[t * WIN + lane] = (v - mu) * rstd * lnw[lane] + lnb[lane];
}

// ------------- precomp0[t][r] = Wih0[r,:] . lnx[t,:] + bih0[r] + bhh0[r] ----------
__global__ __launch_bounds__(256) void precomp_kernel(
    const float* __restrict__ Wih0, const float* __restrict__ bih0,
    const float* __restrict__ bhh0, const float* __restrict__ lnx,
    float* __restrict__ pre) {
    __shared__ float Wt[64][65];
    __shared__ float Xt[64][64];
    int r0 = blockIdx.x * 64;
    int t0 = blockIdx.y * 64;
    for (int i = threadIdx.x; i < 4096; i += 256) Wt[i >> 6][i & 63] = Wih0[r0 * 64 + i];
    for (int i = threadIdx.x; i < 4096; i += 256) Xt[i >> 6][i & 63] = lnx[t0 * 64 + i];
    __syncthreads();
    int lane = threadIdx.x & 63;
    int wv   = threadIdx.x >> 6;
    int row  = r0 + lane;
    float bias = bih0[row] + bhh0[row];
    for (int j = 0; j < 16; ++j) {
        int tl = wv * 16 + j;
        float acc = bias;
        #pragma unroll 8
        for (int k = 0; k < 64; ++k) acc += Wt[lane][k] * Xt[tl][k];
        pre[(size_t)(t0 + tl) * G4 + row] = acc;
    }
}

// ---------------- persistent recurrent kernel: two pipelined groups ----------------
__global__ __launch_bounds__(TPB, 2) void recur_kernel(
    const float* __restrict__ Whh0,
    const float* __restrict__ Wih1, const float* __restrict__ Whh1,
    const float* __restrict__ bih1, const float* __restrict__ bhh1,
    const float* __restrict__ fcw,  const float* __restrict__ pre,
    unsigned int* h0u, unsigned int* h1u,  // [STEPS+1][H] histories, NaN-poisoned
    float* __restrict__ pout) {            // [STEPS][NB] output partials
    const int tid = threadIdx.x;
    const int s   = tid & 31;
    const int LG  = tid >> 5;    // 16 lane-groups of 32

    if (blockIdx.x < NA) {
        // ---------------- layer-0: 32 units/block ----------------
        __shared__ float hA[2][H];
        const int u0 = blockIdx.x * 32;
        const int ul = 2 * LG + (s & 1);     // unit for gate lanes (s<2)
        const bool gl = (s < 2);
        // rows: j=0..7 -> gate=j&3, unit_local=2*LG+(j>>2)
        float w0[8][16];
        #pragma unroll
        for (int j = 0; j < 8; ++j) {
            int row = (j & 3) * H + u0 + 2 * LG + (j >> 2);
            #pragma unroll
            for (int i = 0; i < 16; ++i) {
                w0[j][i] = Whh0[(size_t)row * H + i * 32 + s];
                KEEP(w0[j][i]);
            }
        }
        float c0 = 0.0f;
        // pre for step 0 (gate lanes): pre[t*G4 + g*H + u0+ul]
        float pr[4] = {0.f, 0.f, 0.f, 0.f};
        if (gl) {
            #pragma unroll
            for (int g = 0; g < 4; ++g) pr[g] = pre[(size_t)0 * G4 + g * H + u0 + ul];
        }

        for (int t = 0; t < STEPS; ++t) {
            const int pb = t & 1;
            // issue next step's pre loads (consumed next iteration -> latency hidden)
            float prn[4] = {0.f, 0.f, 0.f, 0.f};
            {
                const int tn = (t + 1) & (STEPS - 1);
                if (gl) {
                    #pragma unroll
                    for (int g = 0; g < 4; ++g) prn[g] = pre[(size_t)tn * G4 + g * H + u0 + ul];
                }
            }
            if (tid < 128) {
                if (t > 0) {
                    const unsigned int* p = h0u + (size_t)t * H + tid * 4;
                    u32x4 v;
                    do { v = ld4_sc01(p); } while (!ok4(v));
                    lds_put4(&hA[pb][tid * 4], v);
                } else {
                    *(float4*)&hA[pb][tid * 4] = make_float4(0.f, 0.f, 0.f, 0.f);
                }
            }
            __syncthreads();

            float acc[8];
            #pragma unroll
            for (int j = 0; j < 8; ++j) {
                float a = 0.0f;
                #pragma unroll
                for (int i = 0; i < 16; ++i) a += w0[j][i] * hA[pb][i * 32 + s];
                acc[j] = a;
            }
            #pragma unroll
            for (int m = 16; m >= 1; m >>= 1) {
                #pragma unroll
                for (int j = 0; j < 8; ++j) acc[j] += __shfl_xor(acc[j], m);
            }
            float hnew = 0.0f;
            if (gl) {
                const int base = (s & 1) * 4;
                float iv = sigf(acc[base + 0] + pr[0]);
                float fv = sigf(acc[base + 1] + pr[1]);
                float gv = tanhfast(acc[base + 2] + pr[2]);
                float ov = sigf(acc[base + 3] + pr[3]);
                c0 = fv * c0 + iv * gv;
                hnew = ov * tanhfast(c0);
            }
            // wave-gather: units 4w..4w+3 live on wave-lanes 0,1,32,33 -> one x4 packet
            unsigned int hb = __float_as_uint(hnew);
            unsigned int b0 = __shfl(hb, 0), b1 = __shfl(hb, 1);
            unsigned int b2 = __shfl(hb, 32), b3 = __shfl(hb, 33);
            if ((tid & 63) == 0) {
                u32x4 pk; pk.x = b0; pk.y = b1; pk.z = b2; pk.w = b3;
                st4_sc01(h0u + (size_t)(t + 1) * H + u0 + (tid >> 6) * 4, pk);
            }
            #pragma unroll
            for (int g = 0; g < 4; ++g) pr[g] = prn[g];
        }
    } else {
        // ---------------- layer-1: 16 units/block ----------------
        __shared__ float hA2[2][H];
        __shared__ float hB2[2][H];
        __shared__ float facc[16];
        const int b1i = blockIdx.x - NA;
        const int u0 = b1i * 16;
        // rows: j = gate 0..3, unit_local = LG
        float w1[4][16], w2[4][16], bias[4];
        #pragma unroll
        for (int j = 0; j < 4; ++j) {
            int row = j * H + u0 + LG;
            bias[j] = bih1[row] + bhh1[row];
            #pragma unroll
            for (int i = 0; i < 16; ++i) {
                w1[j][i] = Wih1[(size_t)row * H + i * 32 + s];
                KEEP(w1[j][i]);
                w2[j][i] = Whh1[(size_t)row * H + i * 32 + s];
                KEEP(w2[j][i]);
            }
        }
        const float fcv = fcw[u0 + LG];
        float c1 = 0.0f;

        for (int t = 0; t < STEPS; ++t) {
            const int pb = t & 1;
            if (tid < 128) {
                const unsigned int* pa = h0u + (size_t)(t + 1) * H + tid * 4;
                u32x4 va; bool da = false;
                if (t > 0) {
                    const unsigned int* pbp = h1u + (size_t)t * H + tid * 4;
                    u32x4 vb; bool db = false;
                    do {
                        if (!da) { va = ld4_sc01(pa); da = ok4(va); }
                        if (!db) { vb = ld4_sc01(pbp); db = ok4(vb); }
                    } while (!(da && db));
                    lds_put4(&hB2[pb][tid * 4], vb);
                } else {
                    do { va = ld4_sc01(pa); da = ok4(va); } while (!da);
                    *(float4*)&hB2[pb][tid * 4] = make_float4(0.f, 0.f, 0.f, 0.f);
                }
                lds_put4(&hA2[pb][tid * 4], va);
            }
            __syncthreads();

            float acc[4];
            #pragma unroll
            for (int j = 0; j < 4; ++j) {
                float a = 0.0f;
                #pragma unroll
                for (int i = 0; i < 16; ++i)
                    a += w1[j][i] * hA2[pb][i * 32 + s] + w2[j][i] * hB2[pb][i * 32 + s];
                acc[j] = a;
            }
            #pragma unroll
            for (int m = 16; m >= 1; m >>= 1) {
                #pragma unroll
                for (int j = 0; j < 4; ++j) acc[j] += __shfl_xor(acc[j], m);
            }
            float hnew = 0.0f;
            if (s == 0) {
                float iv = sigf(acc[0] + bias[0]);
                float fv = sigf(acc[1] + bias[1]);
                float gv = tanhfast(acc[2] + bias[2]);
                float ov = sigf(acc[3] + bias[3]);
                c1 = fv * c1 + iv * gv;
                hnew = ov * tanhfast(c1);
            }
            // wave-gather: units 2w,2w+1 on wave-lanes 0,32 -> one x2 packet
            unsigned int hb = __float_as_uint(hnew);
            unsigned int b0 = __shfl(hb, 0), b2 = __shfl(hb, 32);
            if ((tid & 63) == 0) {
                u32x2 pk; pk.x = b0; pk.y = b2;
                st2_sc01(h1u + (size_t)(t + 1) * H + u0 + (tid >> 6) * 2, pk);
            }
            if (s == 0) facc[LG] = fmaxf(hnew, 0.0f) * fcv;
            __syncthreads();
            if (tid == 0) {
                float pp = 0.0f;
                #pragma unroll
                for (int u = 0; u < 16; ++u) pp += facc[u];
                pout[(size_t)t * NB + b1i] = pp;
            }
        }
    }
}

// ---------------- reduce NB partials per step -> out[t] ----------------
__global__ void reduce_out(const float* __restrict__ pout, const float* __restrict__ fcb,
                           float* __restrict__ out) {
    int t = blockIdx.x;
    int l = threadIdx.x;                 // 64 threads
    float v = (l < NB) ? pout[(size_t)t * NB + l] : 0.0f;
    #pragma unroll
    for (int m = 16; m >= 1; m >>= 1) v += __shfl_xor(v, m);
    if (l == 0) out[t] = v + fcb[0];
}

extern "C" void kernel_launch(void* const* d_in, const int* in_sizes, int n_in,
                              void* d_out, int out_size, void* d_ws, size_t ws_size,
                              hipStream_t stream) {
    const float* batch = (const float*)d_in[0];
    const float* Wih0  = (const float*)d_in[1];
    const float* Whh0  = (const float*)d_in[2];
    const float* bih0  = (const float*)d_in[3];
    const float* bhh0  = (const float*)d_in[4];
    const float* Wih1  = (const float*)d_in[5];
    const float* Whh1  = (const float*)d_in[6];
    const float* bih1  = (const float*)d_in[7];
    const float* bhh1  = (const float*)d_in[8];
    const float* lnw   = (const float*)d_in[9];
    const float* lnb   = (const float*)d_in[10];
    const float* fcw   = (const float*)d_in[11];
    const float* fcb   = (const float*)d_in[12];
    float* out = (float*)d_out;

    // workspace layout (~25.3 MB)
    float*        ws   = (float*)d_ws;
    float*        pre  = ws;                                   // 2048*2048
    float*        lnx  = pre + (size_t)STEPS * G4;             // 2048*64
    float*        pout = lnx + (size_t)STEPS * WIN;            // 2048*NB
    unsigned int* h0u  = (unsigned int*)(pout + (size_t)STEPS * NB);  // 2049*512
    unsigned int* h1u  = h0u + (size_t)(STEPS + 1) * H;        // 2049*512

    // poison both h histories (NaN pattern); slot 0 handled by t==0 branch in-kernel
    (void)hipMemsetAsync(h0u, 0xFF, (size_t)2 * (STEPS + 1) * H * sizeof(unsigned int), stream);

    ln_kernel<<<dim3(STEPS / 4), dim3(256), 0, stream>>>(batch, lnw, lnb, lnx);
    precomp_kernel<<<dim3(G4 / 64, STEPS / 64), dim3(256), 0, stream>>>(Wih0, bih0, bhh0, lnx, pre);
    recur_kernel<<<dim3(NA + NB), dim3(TPB), 0, stream>>>(Whh0, Wih1, Whh1, bih1, bhh1,
                                                          fcw, pre, h0u, h1u, pout);
    reduce_out<<<dim3(STEPS), dim3(64), 0, stream>>>(pout, fcb, out);
}

// Round 7
// 6362.054 us; speedup vs baseline: 98.2201x; 1.0045x over previous
//
#include <hip/hip_runtime.h>
#include <math.h>

// LSTMModel: 2048 sequential steps, 2x LSTMCell(H=512), LN(64) front, fc(512->1).
// R6: weight-residency fix. Root cause of flat perf: (a) "memory" clobbers on the
// poll/publish asm forced weight reloads from L2 every step (256KB/block/step ~1.9us);
// (b) __launch_bounds__(512,2) capped VGPRs at 128/thread so KEEP() spilled to scratch.
// Fix: drop "memory" clobbers (volatile asms already maintain mutual program order;
// loaded value IS the data - no other memory ordering needed) + launch_bounds(512,1)
// for a 512-VGPR budget. Weights now genuinely register-resident.

#define H      512
#define G4     2048
#define WIN    64
#define STEPS  2048
#define NA     16      // layer-0 blocks (32 units each)
#define NB     32      // layer-1 blocks (16 units each)
#define TPB    512
#define POISON 0xFFFFFFFFu

#define KEEP(x) asm("" : "+v"(x))

typedef unsigned int u32x4 __attribute__((ext_vector_type(4)));
typedef unsigned int u32x2 __attribute__((ext_vector_type(2)));

__device__ __forceinline__ float sigf(float x)     { return 1.0f / (1.0f + __expf(-x)); }
__device__ __forceinline__ float tanhfast(float x) { return 2.0f / (1.0f + __expf(-2.0f * x)) - 1.0f; }

// ---- MALL-visible (agent-scope) load/store helpers ----
// NOTE: no "memory" clobber. Volatile asms keep program order among themselves;
// the polled value is the data itself, so no other ordering is required. This
// lets the compiler keep __restrict__ weights in VGPRs across the poll loop.
__device__ __forceinline__ u32x4 ld4_sc01(const unsigned int* p) {
    u32x4 v;
    asm volatile("global_load_dwordx4 %0, %1, off sc0 sc1\n\ts_waitcnt vmcnt(0)"
                 : "=&v"(v) : "v"(p));
    return v;
}
__device__ __forceinline__ void st4_sc01(unsigned int* p, u32x4 v) {
    asm volatile("global_store_dwordx4 %0, %1, off sc0 sc1" :: "v"(p), "v"(v));
}
__device__ __forceinline__ void st2_sc01(unsigned int* p, u32x2 v) {
    asm volatile("global_store_dwordx2 %0, %1, off sc0 sc1" :: "v"(p), "v"(v));
}
__device__ __forceinline__ bool ok4(u32x4 v) {
    return v.x != POISON && v.y != POISON && v.z != POISON && v.w != POISON;
}
__device__ __forceinline__ void lds_put4(float* dst, u32x4 v) {
    float4 f;
    f.x = __uint_as_float(v.x); f.y = __uint_as_float(v.y);
    f.z = __uint_as_float(v.z); f.w = __uint_as_float(v.w);
    *(float4*)dst = f;
}

// ---------------- LayerNorm over sliding windows (parallel over t) ----------------
__global__ void ln_kernel(const float* __restrict__ batch, const float* __restrict__ lnw,
                          const float* __restrict__ lnb, float* __restrict__ lnx) {
    int wave = threadIdx.x >> 6;
    int lane = threadIdx.x & 63;
    int t = blockIdx.x * 4 + wave;
    int src = t - 63 + lane;
    float v = (src >= 0) ? batch[src] : 0.0f;
    float s = v, ss = v * v;
    #pragma unroll
    for (int m = 32; m >= 1; m >>= 1) { s += __shfl_xor(s, m); ss += __shfl_xor(ss, m); }
    float mu   = s * (1.0f / 64.0f);
    float var  = ss * (1.0f / 64.0f) - mu * mu;
    float rstd = rsqrtf(var + 1e-5f);
    lnx[t * WIN + lane] = (v - mu) * rstd * lnw[lane] + lnb[lane];
}

// ------------- precomp0[t][r] = Wih0[r,:] . lnx[t,:] + bih0[r] + bhh0[r] ----------
__global__ __launch_bounds__(256) void precomp_kernel(
    const float* __restrict__ Wih0, const float* __restrict__ bih0,
    const float* __restrict__ bhh0, const float* __restrict__ lnx,
    float* __restrict__ pre) {
    __shared__ float Wt[64][65];
    __shared__ float Xt[64][64];
    int r0 = blockIdx.x * 64;
    int t0 = blockIdx.y * 64;
    for (int i = threadIdx.x; i < 4096; i += 256) Wt[i >> 6][i & 63] = Wih0[r0 * 64 + i];
    for (int i = threadIdx.x; i < 4096; i += 256) Xt[i >> 6][i & 63] = lnx[t0 * 64 + i];
    __syncthreads();
    int lane = threadIdx.x & 63;
    int wv   = threadIdx.x >> 6;
    int row  = r0 + lane;
    float bias = bih0[row] + bhh0[row];
    for (int j = 0; j < 16; ++j) {
        int tl = wv * 16 + j;
        float acc = bias;
        #pragma unroll 8
        for (int k = 0; k < 64; ++k) acc += Wt[lane][k] * Xt[tl][k];
        pre[(size_t)(t0 + tl) * G4 + row] = acc;
    }
}

// ---------------- persistent recurrent kernel: two pipelined groups ----------------
__global__ __launch_bounds__(TPB, 1) void recur_kernel(
    const float* __restrict__ Whh0,
    const float* __restrict__ Wih1, const float* __restrict__ Whh1,
    const float* __restrict__ bih1, const float* __restrict__ bhh1,
    const float* __restrict__ fcw,  const float* __restrict__ pre,
    unsigned int* h0u, unsigned int* h1u,  // [STEPS+1][H] histories, NaN-poisoned
    float* __restrict__ pout) {            // [STEPS][NB] output partials
    const int tid = threadIdx.x;
    const int s   = tid & 31;
    const int LG  = tid >> 5;    // 16 lane-groups of 32

    if (blockIdx.x < NA) {
        // ---------------- layer-0: 32 units/block ----------------
        __shared__ float hA[2][H];
        const int u0 = blockIdx.x * 32;
        const int ul = 2 * LG + (s & 1);     // unit for gate lanes (s<2)
        const bool gl = (s < 2);
        // rows: j=0..7 -> gate=j&3, unit_local=2*LG+(j>>2)
        float w0[8][16];
        #pragma unroll
        for (int j = 0; j < 8; ++j) {
            int row = (j & 3) * H + u0 + 2 * LG + (j >> 2);
            #pragma unroll
            for (int i = 0; i < 16; ++i) {
                w0[j][i] = Whh0[(size_t)row * H + i * 32 + s];
                KEEP(w0[j][i]);
            }
        }
        float c0 = 0.0f;
        // pre for step 0 (gate lanes): pre[t*G4 + g*H + u0+ul]
        float pr[4] = {0.f, 0.f, 0.f, 0.f};
        if (gl) {
            #pragma unroll
            for (int g = 0; g < 4; ++g) pr[g] = pre[(size_t)0 * G4 + g * H + u0 + ul];
        }

        for (int t = 0; t < STEPS; ++t) {
            const int pb = t & 1;
            // issue next step's pre loads (consumed next iteration -> latency hidden)
            float prn[4] = {0.f, 0.f, 0.f, 0.f};
            {
                const int tn = (t + 1) & (STEPS - 1);
                if (gl) {
                    #pragma unroll
                    for (int g = 0; g < 4; ++g) prn[g] = pre[(size_t)tn * G4 + g * H + u0 + ul];
                }
            }
            if (tid < 128) {
                if (t > 0) {
                    const unsigned int* p = h0u + (size_t)t * H + tid * 4;
                    u32x4 v;
                    do { v = ld4_sc01(p); } while (!ok4(v));
                    lds_put4(&hA[pb][tid * 4], v);
                } else {
                    *(float4*)&hA[pb][tid * 4] = make_float4(0.f, 0.f, 0.f, 0.f);
                }
            }
            __syncthreads();

            float acc[8];
            #pragma unroll
            for (int j = 0; j < 8; ++j) {
                float a = 0.0f;
                #pragma unroll
                for (int i = 0; i < 16; ++i) a += w0[j][i] * hA[pb][i * 32 + s];
                acc[j] = a;
            }
            #pragma unroll
            for (int m = 16; m >= 1; m >>= 1) {
                #pragma unroll
                for (int j = 0; j < 8; ++j) acc[j] += __shfl_xor(acc[j], m);
            }
            float hnew = 0.0f;
            if (gl) {
                const int base = (s & 1) * 4;
                float iv = sigf(acc[base + 0] + pr[0]);
                float fv = sigf(acc[base + 1] + pr[1]);
                float gv = tanhfast(acc[base + 2] + pr[2]);
                float ov = sigf(acc[base + 3] + pr[3]);
                c0 = fv * c0 + iv * gv;
                hnew = ov * tanhfast(c0);
            }
            // wave-gather: units 4w..4w+3 live on wave-lanes 0,1,32,33 -> one x4 packet
            unsigned int hb = __float_as_uint(hnew);
            unsigned int b0 = __shfl(hb, 0), b1 = __shfl(hb, 1);
            unsigned int b2 = __shfl(hb, 32), b3 = __shfl(hb, 33);
            if ((tid & 63) == 0) {
                u32x4 pk; pk.x = b0; pk.y = b1; pk.z = b2; pk.w = b3;
                st4_sc01(h0u + (size_t)(t + 1) * H + u0 + (tid >> 6) * 4, pk);
            }
            #pragma unroll
            for (int g = 0; g < 4; ++g) pr[g] = prn[g];
        }
    } else {
        // ---------------- layer-1: 16 units/block ----------------
        __shared__ float hA2[2][H];
        __shared__ float hB2[2][H];
        __shared__ float facc[16];
        const int b1i = blockIdx.x - NA;
        const int u0 = b1i * 16;
        // rows: j = gate 0..3, unit_local = LG
        float w1[4][16], w2[4][16], bias[4];
        #pragma unroll
        for (int j = 0; j < 4; ++j) {
            int row = j * H + u0 + LG;
            bias[j] = bih1[row] + bhh1[row];
            #pragma unroll
            for (int i = 0; i < 16; ++i) {
                w1[j][i] = Wih1[(size_t)row * H + i * 32 + s];
                KEEP(w1[j][i]);
                w2[j][i] = Whh1[(size_t)row * H + i * 32 + s];
                KEEP(w2[j][i]);
            }
        }
        const float fcv = fcw[u0 + LG];
        float c1 = 0.0f;

        for (int t = 0; t < STEPS; ++t) {
            const int pb = t & 1;
            if (tid < 128) {
                const unsigned int* pa = h0u + (size_t)(t + 1) * H + tid * 4;
                u32x4 va; bool da = false;
                if (t > 0) {
                    const unsigned int* pbp = h1u + (size_t)t * H + tid * 4;
                    u32x4 vb; bool db = false;
                    do {
                        if (!da) { va = ld4_sc01(pa); da = ok4(va); }
                        if (!db) { vb = ld4_sc01(pbp); db = ok4(vb); }
                    } while (!(da && db));
                    lds_put4(&hB2[pb][tid * 4], vb);
                } else {
                    do { va = ld4_sc01(pa); da = ok4(va); } while (!da);
                    *(float4*)&hB2[pb][tid * 4] = make_float4(0.f, 0.f, 0.f, 0.f);
                }
                lds_put4(&hA2[pb][tid * 4], va);
            }
            __syncthreads();

            float acc[4];
            #pragma unroll
            for (int j = 0; j < 4; ++j) {
                float a = 0.0f;
                #pragma unroll
                for (int i = 0; i < 16; ++i)
                    a += w1[j][i] * hA2[pb][i * 32 + s] + w2[j][i] * hB2[pb][i * 32 + s];
                acc[j] = a;
            }
            #pragma unroll
            for (int m = 16; m >= 1; m >>= 1) {
                #pragma unroll
                for (int j = 0; j < 4; ++j) acc[j] += __shfl_xor(acc[j], m);
            }
            float hnew = 0.0f;
            if (s == 0) {
                float iv = sigf(acc[0] + bias[0]);
                float fv = sigf(acc[1] + bias[1]);
                float gv = tanhfast(acc[2] + bias[2]);
                float ov = sigf(acc[3] + bias[3]);
                c1 = fv * c1 + iv * gv;
                hnew = ov * tanhfast(c1);
            }
            // wave-gather: units 2w,2w+1 on wave-lanes 0,32 -> one x2 packet
            unsigned int hb = __float_as_uint(hnew);
            unsigned int b0 = __shfl(hb, 0), b2 = __shfl(hb, 32);
            if ((tid & 63) == 0) {
                u32x2 pk; pk.x = b0; pk.y = b2;
                st2_sc01(h1u + (size_t)(t + 1) * H + u0 + (tid >> 6) * 2, pk);
            }
            if (s == 0) facc[LG] = fmaxf(hnew, 0.0f) * fcv;
            __syncthreads();
            if (tid == 0) {
                float pp = 0.0f;
                #pragma unroll
                for (int u = 0; u < 16; ++u) pp += facc[u];
                pout[(size_t)t * NB + b1i] = pp;
            }
        }
    }
}

// ---------------- reduce NB partials per step -> out[t] ----------------
__global__ void reduce_out(const float* __restrict__ pout, const float* __restrict__ fcb,
                           float* __restrict__ out) {
    int t = blockIdx.x;
    int l = threadIdx.x;                 // 64 threads
    float v = (l < NB) ? pout[(size_t)t * NB + l] : 0.0f;
    #pragma unroll
    for (int m = 16; m >= 1; m >>= 1) v += __shfl_xor(v, m);
    if (l == 0) out[t] = v + fcb[0];
}

extern "C" void kernel_launch(void* const* d_in, const int* in_sizes, int n_in,
                              void* d_out, int out_size, void* d_ws, size_t ws_size,
                              hipStream_t stream) {
    const float* batch = (const float*)d_in[0];
    const float* Wih0  = (const float*)d_in[1];
    const float* Whh0  = (const float*)d_in[2];
    const float* bih0  = (const float*)d_in[3];
    const float* bhh0  = (const float*)d_in[4];
    const float* Wih1  = (const float*)d_in[5];
    const float* Whh1  = (const float*)d_in[6];
    const float* bih1  = (const float*)d_in[7];
    const float* bhh1  = (const float*)d_in[8];
    const float* lnw   = (const float*)d_in[9];
    const float* lnb   = (const float*)d_in[10];
    const float* fcw   = (const float*)d_in[11];
    const float* fcb   = (const float*)d_in[12];
    float* out = (float*)d_out;

    // workspace layout (~25.3 MB)
    float*        ws   = (float*)d_ws;
    float*        pre  = ws;                                   // 2048*2048
    float*        lnx  = pre + (size_t)STEPS * G4;             // 2048*64
    float*        pout = lnx + (size_t)STEPS * WIN;            // 2048*NB
    unsigned int* h0u  = (unsigned int*)(pout + (size_t)STEPS * NB);  // 2049*512
    unsigned int* h1u  = h0u + (size_t)(STEPS + 1) * H;        // 2049*512

    // poison both h histories (NaN pattern); slot 0 handled by t==0 branch in-kernel
    (void)hipMemsetAsync(h0u, 0xFF, (size_t)2 * (STEPS + 1) * H * sizeof(unsigned int), stream);

    ln_kernel<<<dim3(STEPS / 4), dim3(256), 0, stream>>>(batch, lnw, lnb, lnx);
    precomp_kernel<<<dim3(G4 / 64, STEPS / 64), dim3(256), 0, stream>>>(Wih0, bih0, bhh0, lnx, pre);
    recur_kernel<<<dim3(NA + NB), dim3(TPB), 0, stream>>>(Whh0, Wih1, Whh1, bih1, bhh1,
                                                          fcw, pre, h0u, h1u, pout);
    reduce_out<<<dim3(STEPS), dim3(64), 0, stream>>>(pout, fcb, out);
}